// Round 6
// baseline (236.865 us; speedup 1.0000x reference)
//
#include <hip/hip_runtime.h>

// SNN conv layer: 3x3x16->64 conv (SAME) on 512x512 NHWC + old_potentials,
// threshold 1.0 -> (spikes, reset potentials).
// R6: bf16 implicit-GEMM, OPERAND-SWAPPED: mfma(W, In) -> D[m=co][n=pixel].
//   C/D row=quad*4+reg = 4 CONSECUTIVE co per lane -> dwordx4 epilogue
//   (R5's mfma(In, W) gave 1 co/pixel per lane -> 192 scalar VMEM ops/thread,
//    epilogue-bound at ~80us despite ~5us of compute).
//   Fragment loads identical to R5 (A/B lane maps are symmetric).

#define H 512
#define W 512
#define CI 16
#define CO 64
#define TX 32
#define TY 8
#define XT 34          // staged x extent (TX + halo)
#define YT 10          // staged y extent (TY + halo)
#define PIX_US 24      // ushorts per pixel slot (16 used; 48B stride)
#define KS 152         // s_w k-stride in elements (304B)

typedef float v4f __attribute__((ext_vector_type(4)));
typedef float f32x4 __attribute__((ext_vector_type(4)));
typedef short short8 __attribute__((ext_vector_type(8)));
typedef unsigned int uint4v __attribute__((ext_vector_type(4)));

__device__ __forceinline__ unsigned int pack2bf(float f0, float f1) {
    unsigned u0 = __builtin_bit_cast(unsigned, f0);
    unsigned u1 = __builtin_bit_cast(unsigned, f1);
    u0 = (u0 + 0x7FFFu + ((u0 >> 16) & 1u)) >> 16;
    u1 = (u1 + 0x7FFFu + ((u1 >> 16) & 1u)) >> 16;
    return u0 | (u1 << 16);
}

__global__ __launch_bounds__(256, 4)
void snn_conv_mfma(const float* __restrict__ in,
                   const float* __restrict__ w,
                   const float* __restrict__ oldp,
                   float* __restrict__ out_spk,
                   float* __restrict__ out_pot)
{
    __shared__ unsigned short s_in[YT * XT * PIX_US];   // 16320 B, [y][x][16 bf16]
    __shared__ unsigned short s_w[CO * KS];             // 19456 B, [co][k] bf16

    const int tid = threadIdx.x;
    const int bx = blockIdx.x & 15;
    const int by = blockIdx.x >> 4;
    const int tx0 = bx * TX, ty0 = by * TY;

    // ---- stage weights -> s_w[co][k] bf16 (transposed from w[k][co])
    {
        const int n  = tid & 63;
        const int kq = tid >> 6;
        #pragma unroll
        for (int kk = 0; kk < 18; ++kk) {
            const int k = kq * 36 + kk * 2;
            const float f0 = w[k * CO + n];
            const float f1 = w[(k + 1) * CO + n];
            *(unsigned int*)&s_w[n * KS + k] = pack2bf(f0, f1);
        }
    }

    // ---- stage input tile bf16, zero halo
    for (int idx = tid; idx < YT * XT; idx += 256) {
        const int ly = idx / XT, lx = idx - ly * XT;
        const int gy = ty0 + ly - 1, gx = tx0 + lx - 1;
        uint4v pk0, pk1;
        if ((unsigned)gy < H && (unsigned)gx < W) {
            const v4f* p = (const v4f*)(in + (gy * W + gx) * CI);
            v4f a = p[0], b = p[1], c = p[2], d = p[3];
            pk0 = (uint4v){pack2bf(a.x, a.y), pack2bf(a.z, a.w),
                           pack2bf(b.x, b.y), pack2bf(b.z, b.w)};
            pk1 = (uint4v){pack2bf(c.x, c.y), pack2bf(c.z, c.w),
                           pack2bf(d.x, d.y), pack2bf(d.z, d.w)};
        } else {
            pk0 = (uint4v)0u;
            pk1 = (uint4v)0u;
        }
        uint4v* dst = (uint4v*)&s_in[idx * PIX_US];
        dst[0] = pk0;
        dst[1] = pk1;
    }
    __syncthreads();

    // ---- wave-level implicit GEMM: M = co (4 tiles), N = pixels (4 tiles)
    const int lane = tid & 63;
    const int wv   = tid >> 6;       // wave 0..3 -> pixel rows 2wv, 2wv+1
    const int r    = lane & 15;      // co within M-tile (A) / pixel within N-tile (B)
    const int quad = lane >> 4;
    const int half = quad & 1;       // ci-half for input k-slice
    const int tsel = quad >> 1;      // tap parity within K-step

    f32x4 acc[4][4] = {};            // [mt = co tile][pt = pixel tile]

    int pbase[4];
    #pragma unroll
    for (int pt = 0; pt < 4; ++pt) {
        const int rl = 2 * wv + (pt >> 1);
        const int xl = (pt & 1) * 16 + r;
        pbase[pt] = (rl * XT + xl) * PIX_US + half * 8;
    }

    const short8 zero8 = {0, 0, 0, 0, 0, 0, 0, 0};

    #pragma unroll
    for (int ks5 = 0; ks5 < 5; ++ks5) {
        const int t0 = ks5 * 2;
        const int t1 = (ks5 == 4) ? 8 : ks5 * 2 + 1;
        const int off0 = ((t0 / 3) * XT + (t0 % 3)) * PIX_US;
        const int off1 = ((t1 / 3) * XT + (t1 % 3)) * PIX_US;
        const int aoff = tsel ? off1 : off0;
        const int koff = (ks5 < 4) ? (ks5 * 32 + quad * 8) : (128 + half * 8);

        short8 wf[4];                // A: weights, m = mt*16 + r, k = quad*8+j
        #pragma unroll
        for (int mt = 0; mt < 4; ++mt)
            wf[mt] = *(const short8*)&s_w[(mt * 16 + r) * KS + koff];

        short8 pf[4];                // B: input, n = pixel = r, k = quad*8+j
        #pragma unroll
        for (int pt = 0; pt < 4; ++pt) {
            short8 a = *(const short8*)&s_in[pbase[pt] + aoff];
            if (ks5 == 4) a = (quad >= 2) ? zero8 : a;   // zero pad k=144..159
            pf[pt] = a;
        }

        #pragma unroll
        for (int mt = 0; mt < 4; ++mt)
            #pragma unroll
            for (int pt = 0; pt < 4; ++pt)
                acc[mt][pt] = __builtin_amdgcn_mfma_f32_16x16x32_bf16(
                    wf[mt], pf[pt], acc[mt][pt], 0, 0, 0);
    }

    // ---- epilogue: D row = co = mt*16 + quad*4 + reg (4 consecutive co!),
    //                D col = pixel = r  -> dwordx4 everywhere
    #pragma unroll
    for (int pt = 0; pt < 4; ++pt) {
        const int gy = ty0 + 2 * wv + (pt >> 1);
        const int gx = tx0 + (pt & 1) * 16 + r;
        const int base0 = (gy * W + gx) * CO + quad * 4;
        #pragma unroll
        for (int mt = 0; mt < 4; ++mt) {
            const int idx = base0 + mt * 16;
            v4f old = *(const v4f*)(oldp + idx);
            const f32x4 a = acc[mt][pt];
            v4f spk, pot;
            #pragma unroll
            for (int c = 0; c < 4; ++c) {
                const float np = a[c] + old[c];
                const bool s = (np >= 1.0f);
                spk[c] = s ? 1.0f : 0.0f;
                pot[c] = s ? 0.0f : np;
            }
            *(v4f*)(out_spk + idx) = spk;
            *(v4f*)(out_pot + idx) = pot;
        }
    }
}

extern "C" void kernel_launch(void* const* d_in, const int* in_sizes, int n_in,
                              void* d_out, int out_size, void* d_ws, size_t ws_size,
                              hipStream_t stream) {
    const float* in   = (const float*)d_in[0];     // (1,512,512,16)
    const float* w    = (const float*)d_in[1];     // (3,3,16,64)
    const float* oldp = (const float*)d_in[2];     // (1,512,512,64)
    float* out_spk = (float*)d_out;
    float* out_pot = out_spk + (size_t)H * W * CO;

    const int grid = (W / TX) * (H / TY);          // 1024 blocks x 256 thr = 4/CU
    snn_conv_mfma<<<grid, 256, 0, stream>>>(in, w, oldp, out_spk, out_pot);
}

// Round 7
// 221.902 us; speedup vs baseline: 1.0674x; 1.0674x over previous
//
#include <hip/hip_runtime.h>

// SNN conv layer: 3x3x16->64 conv (SAME) on 512x512 NHWC + old_potentials,
// threshold 1.0 -> (spikes, reset potentials).
// R7: bf16 implicit-GEMM mfma(W, In) -> D[m=co][n=pixel] (R6 layout, verified).
//   + weights pre-packed to bf16 [co][k] in d_ws by a tiny pre-kernel
//     (was: 36 strided loads + 36 packs per thread per block)
//   + oldp rolling prefetch: pt0 loads issued before MFMA loop, pt+1
//     prefetched during pt's threshold+store (overlaps the 67MB stream)
//   + launch_bounds(256,3): no 128-VGPR spill gamble.

#define H 512
#define W 512
#define CI 16
#define CO 64
#define TX 32
#define TY 8
#define XT 34          // staged x extent (TX + halo)
#define YT 10          // staged y extent (TY + halo)
#define PIX_US 24      // ushorts per pixel slot (16 used; 48B stride)
#define KS 152         // s_w / ws k-stride in elements (304B)

typedef float v4f __attribute__((ext_vector_type(4)));
typedef float f32x4 __attribute__((ext_vector_type(4)));
typedef short short8 __attribute__((ext_vector_type(8)));
typedef unsigned int uint4v __attribute__((ext_vector_type(4)));

__device__ __forceinline__ unsigned int pack2bf(float f0, float f1) {
    unsigned u0 = __builtin_bit_cast(unsigned, f0);
    unsigned u1 = __builtin_bit_cast(unsigned, f1);
    u0 = (u0 + 0x7FFFu + ((u0 >> 16) & 1u)) >> 16;
    u1 = (u1 + 0x7FFFu + ((u1 >> 16) & 1u)) >> 16;
    return u0 | (u1 << 16);
}

// ---- pre-kernel: w[k][co] fp32 -> ws[co][k] bf16 (4608 pairs, 18 blocks)
__global__ void conv_w_pack(const float* __restrict__ w,
                            unsigned short* __restrict__ wbf) {
    const int e = blockIdx.x * 256 + threadIdx.x;   // [0, 4608)
    const int k2 = e >> 6;                          // 0..71
    const int n  = e & 63;
    const int k  = k2 * 2;                          // 0..142
    const float f0 = w[k * CO + n];                 // lanes: n consecutive -> coalesced
    const float f1 = w[(k + 1) * CO + n];
    *(unsigned int*)&wbf[n * KS + k] = pack2bf(f0, f1);
}

__global__ __launch_bounds__(256, 3)
void snn_conv_mfma(const float* __restrict__ in,
                   const unsigned short* __restrict__ wbf,
                   const float* __restrict__ oldp,
                   float* __restrict__ out_spk,
                   float* __restrict__ out_pot)
{
    __shared__ unsigned short s_in[YT * XT * PIX_US];   // 16320 B, [y][x][16 bf16]
    __shared__ unsigned short s_w[CO * KS];             // 19456 B, [co][k] bf16

    const int tid = threadIdx.x;
    const int bx = blockIdx.x & 15;
    const int by = blockIdx.x >> 4;
    const int tx0 = bx * TX, ty0 = by * TY;

    // ---- stage weights: straight 16B copy of pre-packed blob (19456 B = 1216 v4)
    {
        const uint4v* wsrc = (const uint4v*)wbf;
        uint4v* wdst = (uint4v*)s_w;
        #pragma unroll
        for (int i = 0; i < 5; ++i) {
            const int idx = tid + i * 256;
            if (idx < (CO * KS * 2) / 16) wdst[idx] = wsrc[idx];
        }
    }

    // ---- stage input tile bf16, zero halo
    for (int idx = tid; idx < YT * XT; idx += 256) {
        const int ly = idx / XT, lx = idx - ly * XT;
        const int gy = ty0 + ly - 1, gx = tx0 + lx - 1;
        uint4v pk0, pk1;
        if ((unsigned)gy < H && (unsigned)gx < W) {
            const v4f* p = (const v4f*)(in + (gy * W + gx) * CI);
            v4f a = p[0], b = p[1], c = p[2], d = p[3];
            pk0 = (uint4v){pack2bf(a.x, a.y), pack2bf(a.z, a.w),
                           pack2bf(b.x, b.y), pack2bf(b.z, b.w)};
            pk1 = (uint4v){pack2bf(c.x, c.y), pack2bf(c.z, c.w),
                           pack2bf(d.x, d.y), pack2bf(d.z, d.w)};
        } else {
            pk0 = (uint4v)0u;
            pk1 = (uint4v)0u;
        }
        uint4v* dst = (uint4v*)&s_in[idx * PIX_US];
        dst[0] = pk0;
        dst[1] = pk1;
    }

    // ---- lane decomposition
    const int lane = tid & 63;
    const int wv   = tid >> 6;       // wave 0..3 -> pixel rows 2wv, 2wv+1
    const int r    = lane & 15;      // co within M-tile (A) / pixel within N-tile (B)
    const int quad = lane >> 4;
    const int half = quad & 1;       // ci-half for input k-slice
    const int tsel = quad >> 1;      // tap parity within K-step

    // epilogue addresses + EARLY prefetch of pt=0's oldp (overlaps MFMA phase)
    int ebase[4];
    #pragma unroll
    for (int pt = 0; pt < 4; ++pt) {
        const int gy = ty0 + 2 * wv + (pt >> 1);
        const int gx = tx0 + (pt & 1) * 16 + r;
        ebase[pt] = (gy * W + gx) * CO + quad * 4;
    }
    v4f oldb[2][4];
    #pragma unroll
    for (int mt = 0; mt < 4; ++mt)
        oldb[0][mt] = *(const v4f*)(oldp + ebase[0] + mt * 16);

    __syncthreads();

    int pbase[4];
    #pragma unroll
    for (int pt = 0; pt < 4; ++pt) {
        const int rl = 2 * wv + (pt >> 1);
        const int xl = (pt & 1) * 16 + r;
        pbase[pt] = (rl * XT + xl) * PIX_US + half * 8;
    }

    f32x4 acc[4][4] = {};            // [mt = co tile][pt = pixel tile]
    const short8 zero8 = {0, 0, 0, 0, 0, 0, 0, 0};

    #pragma unroll
    for (int ks5 = 0; ks5 < 5; ++ks5) {
        const int t0 = ks5 * 2;
        const int t1 = (ks5 == 4) ? 8 : ks5 * 2 + 1;
        const int off0 = ((t0 / 3) * XT + (t0 % 3)) * PIX_US;
        const int off1 = ((t1 / 3) * XT + (t1 % 3)) * PIX_US;
        const int aoff = tsel ? off1 : off0;
        const int koff = (ks5 < 4) ? (ks5 * 32 + quad * 8) : (128 + half * 8);

        short8 wf[4];                // A: weights, m = mt*16 + r, k = quad*8+j
        #pragma unroll
        for (int mt = 0; mt < 4; ++mt)
            wf[mt] = *(const short8*)&s_w[(mt * 16 + r) * KS + koff];

        short8 pf[4];                // B: input, n = pixel = r, k = quad*8+j
        #pragma unroll
        for (int pt = 0; pt < 4; ++pt) {
            short8 a = *(const short8*)&s_in[pbase[pt] + aoff];
            if (ks5 == 4) a = (quad >= 2) ? zero8 : a;   // zero pad k=144..159
            pf[pt] = a;
        }

        #pragma unroll
        for (int mt = 0; mt < 4; ++mt)
            #pragma unroll
            for (int pt = 0; pt < 4; ++pt)
                acc[mt][pt] = __builtin_amdgcn_mfma_f32_16x16x32_bf16(
                    wf[mt], pf[pt], acc[mt][pt], 0, 0, 0);
    }

    // ---- epilogue, software-pipelined: prefetch pt+1 oldp, then process pt.
    // D row = co = mt*16 + quad*4 + reg (4 consecutive co), col = pixel = r.
    #pragma unroll
    for (int pt = 0; pt < 4; ++pt) {
        const int cur = pt & 1;
        if (pt < 3) {
            #pragma unroll
            for (int mt = 0; mt < 4; ++mt)
                oldb[1 - cur][mt] = *(const v4f*)(oldp + ebase[pt + 1] + mt * 16);
        }
        #pragma unroll
        for (int mt = 0; mt < 4; ++mt) {
            const int idx = ebase[pt] + mt * 16;
            const v4f old = oldb[cur][mt];
            const f32x4 a = acc[mt][pt];
            v4f spk, pot;
            #pragma unroll
            for (int c = 0; c < 4; ++c) {
                const float np = a[c] + old[c];
                const bool s = (np >= 1.0f);
                spk[c] = s ? 1.0f : 0.0f;
                pot[c] = s ? 0.0f : np;
            }
            *(v4f*)(out_spk + idx) = spk;
            *(v4f*)(out_pot + idx) = pot;
        }
    }
}

extern "C" void kernel_launch(void* const* d_in, const int* in_sizes, int n_in,
                              void* d_out, int out_size, void* d_ws, size_t ws_size,
                              hipStream_t stream) {
    const float* in   = (const float*)d_in[0];     // (1,512,512,16)
    const float* w    = (const float*)d_in[1];     // (3,3,16,64)
    const float* oldp = (const float*)d_in[2];     // (1,512,512,64)
    float* out_spk = (float*)d_out;
    float* out_pot = out_spk + (size_t)H * W * CO;
    unsigned short* wbf = (unsigned short*)d_ws;   // CO*KS bf16 = 19456 B

    conv_w_pack<<<18, 256, 0, stream>>>(w, wbf);   // 18*256 = 4608 pairs, exact
    const int grid = (W / TX) * (H / TY);          // 1024 blocks x 256 thr
    snn_conv_mfma<<<grid, 256, 0, stream>>>(in, wbf, oldp, out_spk, out_pot);
}